// Round 16
// baseline (602.050 us; speedup 1.0000x reference)
//
#include <hip/hip_runtime.h>
#include <hip/hip_fp16.h>

// Residual VQ on MI355X (gfx950) — MFMA distance engine, barrier-free,
// register trackers + shfl class-reduce + owner handoff.
// z: [8, 32768, 32] f32; codebooks: [10, 512, 32] f32.
// Outputs (flat f32 in d_out): quantized [B,N,D], indices [B,N,Q] (as float),
// commit_loss [Q] (zeros).
//
// R16 = R15 (prep fragments, 1-wave blocks, packed u32 keys, coop scans —
// absmax 0.0, 512 us) with 4 cuts:
//  (1) uniform-K shift: argmin/pt invariant to +rr, so C-init = cc + K
//      (K = rrmax+biasW wave-uniform): 1 add/ct (was 16). v''>=biasW>0
//      keeps u32-float ordering; same window/trunc margins as R15.
//  (2) med3_u32 tracker: m2=med3(m2,m1,key); m1=min(m1,key) — 2 ops/value.
//  (3) trackers stay in registers; per-point class-min via 4x shfl_xor
//      u32-min in the 16-lane group; adm/scan flags + id to owner lane via
//      stride-19 admbuf (no 6.5 KB publish, no sequential 16-class loop).
//  (4) LDS 17.4 -> ~11.3 KB + __launch_bounds__(64,4): 1.7 -> ~3.3 waves/SIMD.
// Exact math (numpy tree, ST chain), split bit-pattern, delta, prep/replay
// bit-identical to the proven R15.

#define RVQ_Q 10
#define RVQ_C 512
#define RVQ_D 32

static constexpr int  NPTS      = 262144;
static constexpr long IDX_OFF   = (long)NPTS * RVQ_D;
static constexpr long LOSS_OFF  = IDX_OFF + (long)NPTS * RVQ_Q;
static constexpr int  BPTS      = 64;            // points per block (1 wave)
static constexpr int  SCB_U4    = RVQ_Q * 32 * 8 * 16;   // 40960 uint4
static constexpr long NORM_OFF  = (long)SCB_U4 * 4;      // floats into scratch
static constexpr unsigned KMASK = 0xFFFFFE00u;   // drop 9 bits for cnd

typedef __attribute__((ext_vector_type(32))) float f32x32;
typedef __attribute__((ext_vector_type(8)))  short short8;
typedef __attribute__((ext_vector_type(4)))  float f32x4;

// ---------------------------------------------------------------------------
// reference-exact numpy reduction tree (proven absmax 0.0 in R1/R3-R15)
__device__ __forceinline__ float tree_dot(const f32x32& x, const f32x32& y) {
    float a[8];
#pragma unroll
    for (int j = 0; j < 8; ++j) a[j] = x[j] * y[j];
#pragma unroll
    for (int j = 8; j < RVQ_D; ++j) a[j & 7] = fmaf(x[j], y[j], a[j & 7]);
    return ((a[0] + a[1]) + (a[2] + a[3])) + ((a[4] + a[5]) + (a[6] + a[7]));
}

__device__ __forceinline__ f32x32 st_update(const f32x32& r, const f32x32& gv) {
    const f32x32 tt  = gv - r;
    const f32x32 qst = r + tt;
    return r - qst;
}

__device__ __forceinline__ short8 as_s8(uint4 u) {
    union { uint4 a; short8 b; } x; x.a = u; return x.b;
}
__device__ __forceinline__ unsigned pk_hi(float v0, float v1) {
    return (__float_as_uint(v0) >> 16) | (__float_as_uint(v1) & 0xFFFF0000u);
}
__device__ __forceinline__ float lo_rem(float v) {
    return v - __uint_as_float(__float_as_uint(v) & 0xFFFF0000u);
}
__device__ __forceinline__ unsigned umn(unsigned a, unsigned b) { return a < b ? a : b; }

// ---------------------------------------------------------------------------
// Kernel P: codebook -> bf16 hi/lo MFMA fragments + exact norms (R14-proven).
__global__ __launch_bounds__(64) void rvq_prep(const float* __restrict__ cb,
                                               uint4* __restrict__ scb,
                                               float* __restrict__ normg) {
    const int cnd = blockIdx.x * 64 + threadIdx.x;       // 0..5119
    const f32x32 c = *(const f32x32*)(cb + (long)cnd * RVQ_D);
    normg[cnd] = tree_dot(c, c);
    const int q = cnd >> 9, cq = cnd & 511, ct = cq >> 4, col = cq & 15;
    const long base = (long)(q * 32 + ct) * 128 + col;
#pragma unroll
    for (int g = 0; g < 4; ++g)
#pragma unroll
        for (int sp = 0; sp < 2; ++sp) {
            unsigned u[4];
#pragma unroll
            for (int pr = 0; pr < 4; ++pr) {
                const int j = g * 8 + pr * 2;
                float v0 = c[j], v1 = c[j + 1];
                if (sp == 1) { v0 = lo_rem(v0); v1 = lo_rem(v1); }
                u[pr] = pk_hi(v0, v1);
            }
            scb[base + (g * 2 + sp) * 16] = make_uint4(u[0], u[1], u[2], u[3]);
        }
}

// ---------------------------------------------------------------------------
// Kernel S: search. ONE wave per block, 64 points, no __syncthreads.
__global__ __launch_bounds__(64, 4) void rvq_search(const float* __restrict__ z,
                                                    const float* __restrict__ cb,
                                                    const uint4* __restrict__ scb,
                                                    const float* __restrict__ normg,
                                                    float* __restrict__ iout) {
    __shared__ uint4 ptfrag[BPTS * 8];            // 4 KB point bf16 splits (-2r)
    __shared__ float snorm_l[RVQ_C];              // 2 KB exact norms
    __shared__ float rrbuf[BPTS];                 // 256 B
    __shared__ unsigned admbuf[BPTS * 19];        // 4.75 KB (stride 19: no conflicts)

    const int t    = threadIdx.x;          // 0..63 == lane
    const int col  = t & 15;
    const int g    = t >> 4;
    const int sw0  = g ^ (col & 7);
    const int sw1  = (4 + g) ^ (col & 7);
    const long p   = (long)blockIdx.x * BPTS + t;

    f32x32 r = *(const f32x32*)(z + p * RVQ_D);

#pragma unroll 1
    for (int q = 0; q < RVQ_Q; ++q) {
        const float* cbq  = cb + (long)q * RVQ_C * RVQ_D;
        const uint4* scbq = scb + (long)q * 4096;

        // ---- norms -> LDS + ccm (wave max), rr + rrmax (wave max)
        float ccm = 0.0f;
#pragma unroll
        for (int n = 0; n < 8; ++n) {
            const float v = normg[q * RVQ_C + t + 64 * n];
            snorm_l[t + 64 * n] = v;
            ccm = fmaxf(ccm, v);
        }
#pragma unroll
        for (int m_ = 1; m_ <= 32; m_ <<= 1) ccm = fmaxf(ccm, __shfl_xor(ccm, m_, 64));

        const float rr = tree_dot(r, r);
        rrbuf[t] = rr;
        float rrmax = rr;
#pragma unroll
        for (int m_ = 1; m_ <= 32; m_ <<= 1) rrmax = fmaxf(rrmax, __shfl_xor(rrmax, m_, 64));
        const float biasW = (rrmax + ccm) * 0.001953125f;   // 2^-9 window
        const float K     = rrmax + biasW;                  // uniform shift

        // ---- E phase: -2r bf16 split -> ptfrag (proven bit-pattern)
        {
            const f32x32 s = -2.0f * r;
#pragma unroll
            for (int sp = 0; sp < 2; ++sp)
#pragma unroll
                for (int gg = 0; gg < 4; ++gg) {
                    unsigned u[4];
#pragma unroll
                    for (int pr = 0; pr < 4; ++pr) {
                        const int j = gg * 8 + pr * 2;
                        float v0 = s[j], v1 = s[j + 1];
                        if (sp == 1) { v0 = lo_rem(v0); v1 = lo_rem(v1); }
                        u[pr] = pk_hi(v0, v1);
                    }
                    ptfrag[t * 8 + ((sp * 4 + gg) ^ (t & 7))] =
                        make_uint4(u[0], u[1], u[2], u[3]);
                }
        }

        // ---- hoist A fragments (registers for whole sweep)
        uint4 ahr[4], alr[4];
#pragma unroll
        for (int TL = 0; TL < 4; ++TL) {
            ahr[TL] = ptfrag[(TL * 16 + col) * 8 + sw0];
            alr[TL] = ptfrag[(TL * 16 + col) * 8 + sw1];
        }

        // ---- packed-key trackers (registers only)
        unsigned m1k[4][4], m2k[4][4];
#pragma unroll
        for (int a = 0; a < 4; ++a)
#pragma unroll
            for (int b = 0; b < 4; ++b) { m1k[a][b] = 0xFFFFFFFFu; m2k[a][b] = 0xFFFFFFFFu; }

        int cndv = col;

        // ---- sweep: fragments from L2, zero barriers
#pragma unroll 2
        for (int ct = 0; ct < 32; ++ct) {
            const short8 bh = as_s8(scbq[ct * 128 + g * 32 + col]);
            const short8 bl = as_s8(scbq[ct * 128 + g * 32 + col + 16]);
            const float cK = snorm_l[ct * 16 + col] + K;   // 1 add (uniform-K)
            const f32x4 accin = {cK, cK, cK, cK};
#pragma unroll
            for (int TL = 0; TL < 4; ++TL) {
                const short8 ah = as_s8(ahr[TL]);
                const short8 al = as_s8(alr[TL]);
                f32x4 acc = __builtin_amdgcn_mfma_f32_16x16x32_bf16(ah, bh, accin, 0, 0, 0);
                acc = __builtin_amdgcn_mfma_f32_16x16x32_bf16(al, bh, acc, 0, 0, 0);
                acc = __builtin_amdgcn_mfma_f32_16x16x32_bf16(ah, bl, acc, 0, 0, 0);
#pragma unroll
                for (int i = 0; i < 4; ++i) {
                    const unsigned key = (__float_as_uint(acc[i]) & KMASK) | (unsigned)cndv;
                    // m2 = median(m2, m1, key); m1 = min(m1, key)
                    asm("v_med3_u32 %0, %1, %2, %3"
                        : "=v"(m2k[TL][i]) : "v"(m2k[TL][i]), "v"(m1k[TL][i]), "v"(key));
                    m1k[TL][i] = umn(m1k[TL][i], key);
                }
            }
            cndv += 16;
        }

        // ---- per-(point,class) checks in tracker lanes; handoff to owners
#pragma unroll
        for (int TL = 0; TL < 4; ++TL)
#pragma unroll
            for (int i = 0; i < 4; ++i) {
                unsigned v = m1k[TL][i];
#pragma unroll
                for (int m_ = 1; m_ <= 8; m_ <<= 1) v = umn(v, (unsigned)__shfl_xor((int)v, m_, 64));
                const int pt = TL * 16 + 4 * g + i;
                const float thrf = __uint_as_float(v & KMASK) +
                                   (rrbuf[pt] + ccm) * 0.001953125f;
                const bool adm = __uint_as_float(m1k[TL][i] & KMASK) <= thrf;
                const bool scn = __uint_as_float(m2k[TL][i] & KMASK) <= thrf;
                admbuf[pt * 19 + col] = (m1k[TL][i] & 511u) |
                                        ((adm && !scn) ? 0x10000u : 0u) |
                                        (scn ? 0x20000u : 0u);
            }

        // ---- owner phase: exact evals + (rare) cooperative class scans
        float bd = __builtin_inff(); int bi = 0;
        unsigned smask = 0;
        {
            auto evalExact = [&](int cnd) {
                const f32x32 cvv = *(const f32x32*)(cbq + (long)cnd * RVQ_D);
                const float d = fmaf(-2.0f, tree_dot(r, cvv), rr) + snorm_l[cnd];
                if (d < bd || (d == bd && cnd < bi)) { bd = d; bi = cnd; }
            };
#pragma unroll 1
            for (int c = 0; c < 16; ++c) {
                const unsigned v = admbuf[t * 19 + c];
                smask |= ((v >> 17) & 1u) << c;
                if (v & 0x10000u) evalExact((int)(v & 511u));
            }

            // cooperative full-class scans (R15-proven)
            unsigned long long bal = __ballot(smask != 0);
            const int l31 = t & 31;
            while (bal) {
                const int b = (int)__builtin_ctzll(bal); bal &= bal - 1;
                unsigned sm = (unsigned)__shfl((int)smask, b, 64);
                f32x32 rb;
#pragma unroll
                for (int j = 0; j < RVQ_D; ++j) rb[j] = __shfl(r[j], b, 64);
                const float rrb = __shfl(rr, b, 64);
                while (sm) {
                    const int c = (int)__builtin_ctz(sm); sm &= sm - 1;
                    int  ci = l31 * 16 + c;
                    const f32x32 cvv = *(const f32x32*)(cbq + (long)ci * RVQ_D);
                    float d = fmaf(-2.0f, tree_dot(rb, cvv), rrb) + snorm_l[ci];
#pragma unroll
                    for (int m_ = 1; m_ <= 32; m_ <<= 1) {
                        const float od = __shfl_xor(d, m_, 64);
                        const int   oi = __shfl_xor(ci, m_, 64);
                        if (od < d || (od == d && oi < ci)) { d = od; ci = oi; }
                    }
                    if (t == b) {
                        if (d < bd || (d == bd && ci < bi)) { bd = d; bi = ci; }
                    }
                }
            }
        }

        iout[p * RVQ_Q + q] = (float)bi;
        const f32x32 gw = *(const f32x32*)(cbq + (long)bi * RVQ_D);
        r = st_update(r, gw);
    }
}

// ---------------------------------------------------------------------------
// Replay: bit-exact straight-through chain from stored indices (proven
// pre+post-timing R3-R15). Overwrites the scratch region with quantized.
__global__ __launch_bounds__(256) void rvq_replay(const float* __restrict__ z,
                                                  const float* __restrict__ cb,
                                                  float* __restrict__ out) {
    const int p = blockIdx.x * 256 + threadIdx.x;

    float r[RVQ_D], oacc[RVQ_D];
    {
        const float4* zp = (const float4*)(z + (long)p * RVQ_D);
#pragma unroll
        for (int w = 0; w < 8; ++w) {
            const float4 v = zp[w];
            r[w * 4 + 0] = v.x; r[w * 4 + 1] = v.y;
            r[w * 4 + 2] = v.z; r[w * 4 + 3] = v.w;
        }
    }
#pragma unroll
    for (int d = 0; d < RVQ_D; ++d) oacc[d] = 0.0f;

#pragma unroll 1
    for (int q = 0; q < RVQ_Q; ++q) {
        const int idx = (int)out[IDX_OFF + (long)p * RVQ_Q + q];
        const float4* cwb = (const float4*)(cb + ((long)q * RVQ_C + idx) * RVQ_D);
        float cwv[RVQ_D];
#pragma unroll
        for (int w = 0; w < 8; ++w) {
            const float4 v = cwb[w];
            cwv[w * 4 + 0] = v.x; cwv[w * 4 + 1] = v.y;
            cwv[w * 4 + 2] = v.z; cwv[w * 4 + 3] = v.w;
        }
#pragma unroll
        for (int d = 0; d < RVQ_D; ++d) {
            const float qst = r[d] + (cwv[d] - r[d]);
            oacc[d] += qst;
            r[d] = r[d] - qst;
        }
    }

    float4* qo = (float4*)(out + (long)p * RVQ_D);
#pragma unroll
    for (int w = 0; w < 8; ++w) {
        float4 v;
        v.x = oacc[w * 4 + 0]; v.y = oacc[w * 4 + 1];
        v.z = oacc[w * 4 + 2]; v.w = oacc[w * 4 + 3];
        qo[w] = v;
    }

    if (p < RVQ_Q) out[LOSS_OFF + p] = 0.0f;
}

// ---------------------------------------------------------------------------
extern "C" void kernel_launch(void* const* d_in, const int* in_sizes, int n_in,
                              void* d_out, int out_size, void* d_ws, size_t ws_size,
                              hipStream_t stream) {
    const float* z  = (const float*)d_in[0];
    const float* cb = (const float*)d_in[1];
    float* out = (float*)d_out;
    (void)d_ws; (void)ws_size;   // no workspace (R6 lesson)

    // scratch inside the quantized region (rewritten every call; replay
    // overwrites it at the end — R4/R5/R14/R15-proven pattern)
    uint4* scb   = (uint4*)out;                 // 655 KB fragments
    float* normg = out + NORM_OFF;              // 5120 exact norms
    float* iout  = out + IDX_OFF;

    rvq_prep  <<<(RVQ_Q * RVQ_C) / 64, 64, 0, stream>>>(cb, scb, normg);
    rvq_search<<<NPTS / BPTS, BPTS, 0, stream>>>(z, cb, scb, normg, iout);
    rvq_replay<<<NPTS / 256, 256, 0, stream>>>(z, cb, out);
}

// Round 17
// 582.066 us; speedup vs baseline: 1.0343x; 1.0343x over previous
//
#include <hip/hip_runtime.h>
#include <hip/hip_fp16.h>

// Residual VQ on MI355X (gfx950) — MFMA distance engine, barrier-free,
// packed-key tracker + wave-cooperative exact rescue.
// z: [8, 32768, 32] f32; codebooks: [10, 512, 32] f32.
// Outputs (flat f32 in d_out): quantized [B,N,D], indices [B,N,Q] (as float),
// commit_loss [Q] (zeros).
//
// R17 = R15's proven structure (512 us, absmax 0.0: prep fragments, 1-wave
// blocks, packed u32 keys m1/m2 in registers, LDS publish, owner R-phase,
// wave-cooperative scans) + ONLY the two R16 numerics that are proven
// correct (R16 absmax 0.0) and cheap:
//  (1) uniform-K C-init: accin = cc + K, K = rrmax+biasW (argmin/pt
//      invariant to +rr) — 1 add/ct, kills the 16 C-init adds and the
//      rrb4 hoist;
//  (2) med3_u32 tracker: m2 = med3(m2,m1,key); m1 = min(m1,key).
// R16's handoff restructure (shfl class-reduce + admbuf) REVERTED — it
// cost more DS/VALU than it saved (512->602 us).
// Exact math (numpy tree, ST chain), split bit-pattern, window, prep/replay
// bit-identical to the proven R15/R16.

#define RVQ_Q 10
#define RVQ_C 512
#define RVQ_D 32

static constexpr int  NPTS      = 262144;
static constexpr long IDX_OFF   = (long)NPTS * RVQ_D;
static constexpr long LOSS_OFF  = IDX_OFF + (long)NPTS * RVQ_Q;
static constexpr int  BPTS      = 64;            // points per block (1 wave)
static constexpr int  SCB_U4    = RVQ_Q * 32 * 8 * 16;   // 40960 uint4
static constexpr long NORM_OFF  = (long)SCB_U4 * 4;      // floats into scratch
static constexpr unsigned KMASK = 0xFFFFFE00u;   // drop 9 bits for cnd

typedef __attribute__((ext_vector_type(32))) float f32x32;
typedef __attribute__((ext_vector_type(8)))  short short8;
typedef __attribute__((ext_vector_type(4)))  float f32x4;

// ---------------------------------------------------------------------------
// reference-exact numpy reduction tree (proven absmax 0.0 in R1/R3-R16)
__device__ __forceinline__ float tree_dot(const f32x32& x, const f32x32& y) {
    float a[8];
#pragma unroll
    for (int j = 0; j < 8; ++j) a[j] = x[j] * y[j];
#pragma unroll
    for (int j = 8; j < RVQ_D; ++j) a[j & 7] = fmaf(x[j], y[j], a[j & 7]);
    return ((a[0] + a[1]) + (a[2] + a[3])) + ((a[4] + a[5]) + (a[6] + a[7]));
}

__device__ __forceinline__ f32x32 st_update(const f32x32& r, const f32x32& gv) {
    const f32x32 tt  = gv - r;
    const f32x32 qst = r + tt;
    return r - qst;
}

__device__ __forceinline__ short8 as_s8(uint4 u) {
    union { uint4 a; short8 b; } x; x.a = u; return x.b;
}
__device__ __forceinline__ unsigned pk_hi(float v0, float v1) {
    return (__float_as_uint(v0) >> 16) | (__float_as_uint(v1) & 0xFFFF0000u);
}
__device__ __forceinline__ float lo_rem(float v) {
    return v - __uint_as_float(__float_as_uint(v) & 0xFFFF0000u);
}
__device__ __forceinline__ unsigned umn(unsigned a, unsigned b) { return a < b ? a : b; }

// ---------------------------------------------------------------------------
// Kernel P: codebook -> bf16 hi/lo MFMA fragments + exact norms (R14-proven).
__global__ __launch_bounds__(64) void rvq_prep(const float* __restrict__ cb,
                                               uint4* __restrict__ scb,
                                               float* __restrict__ normg) {
    const int cnd = blockIdx.x * 64 + threadIdx.x;       // 0..5119
    const f32x32 c = *(const f32x32*)(cb + (long)cnd * RVQ_D);
    normg[cnd] = tree_dot(c, c);
    const int q = cnd >> 9, cq = cnd & 511, ct = cq >> 4, col = cq & 15;
    const long base = (long)(q * 32 + ct) * 128 + col;
#pragma unroll
    for (int g = 0; g < 4; ++g)
#pragma unroll
        for (int sp = 0; sp < 2; ++sp) {
            unsigned u[4];
#pragma unroll
            for (int pr = 0; pr < 4; ++pr) {
                const int j = g * 8 + pr * 2;
                float v0 = c[j], v1 = c[j + 1];
                if (sp == 1) { v0 = lo_rem(v0); v1 = lo_rem(v1); }
                u[pr] = pk_hi(v0, v1);
            }
            scb[base + (g * 2 + sp) * 16] = make_uint4(u[0], u[1], u[2], u[3]);
        }
}

// ---------------------------------------------------------------------------
// Kernel S: search. ONE wave per block, 64 points, no __syncthreads.
__global__ __launch_bounds__(64, 2) void rvq_search(const float* __restrict__ z,
                                                    const float* __restrict__ cb,
                                                    const uint4* __restrict__ scb,
                                                    const float* __restrict__ normg,
                                                    float* __restrict__ iout) {
    __shared__ uint4 ptfrag[BPTS * 8];            // 8 KB point bf16 splits (-2r)
    __shared__ float snorm_l[RVQ_C];              // 2 KB exact norms
    __shared__ float rrbuf[BPTS];                 // 256 B
    __shared__ unsigned m1key_s[BPTS * 17];       // 4.25 KB
    __shared__ unsigned short m2h_s[BPTS * 17];   // 2.1 KB

    const int t    = threadIdx.x;          // 0..63 == lane
    const int col  = t & 15;
    const int g    = t >> 4;
    const int sw0  = g ^ (col & 7);
    const int sw1  = (4 + g) ^ (col & 7);
    const long p   = (long)blockIdx.x * BPTS + t;

    f32x32 r = *(const f32x32*)(z + p * RVQ_D);

#pragma unroll 1
    for (int q = 0; q < RVQ_Q; ++q) {
        const float* cbq  = cb + (long)q * RVQ_C * RVQ_D;
        const uint4* scbq = scb + (long)q * 4096;

        // ---- norms -> LDS + ccm (wave max), rr + rrmax (wave max)
        float ccm = 0.0f;
#pragma unroll
        for (int n = 0; n < 8; ++n) {
            const float v = normg[q * RVQ_C + t + 64 * n];
            snorm_l[t + 64 * n] = v;
            ccm = fmaxf(ccm, v);
        }
#pragma unroll
        for (int m_ = 1; m_ <= 32; m_ <<= 1) ccm = fmaxf(ccm, __shfl_xor(ccm, m_, 64));

        const float rr = tree_dot(r, r);
        rrbuf[t] = rr;
        float rrmax = rr;
#pragma unroll
        for (int m_ = 1; m_ <= 32; m_ <<= 1) rrmax = fmaxf(rrmax, __shfl_xor(rrmax, m_, 64));
        const float biasW = (rrmax + ccm) * 0.001953125f;   // 2^-9 window
        const float K     = rrmax + biasW;                  // uniform shift (R16-proven)

        // ---- E phase: -2r bf16 split -> ptfrag (proven bit-pattern)
        {
            const f32x32 s = -2.0f * r;
#pragma unroll
            for (int sp = 0; sp < 2; ++sp)
#pragma unroll
                for (int gg = 0; gg < 4; ++gg) {
                    unsigned u[4];
#pragma unroll
                    for (int pr = 0; pr < 4; ++pr) {
                        const int j = gg * 8 + pr * 2;
                        float v0 = s[j], v1 = s[j + 1];
                        if (sp == 1) { v0 = lo_rem(v0); v1 = lo_rem(v1); }
                        u[pr] = pk_hi(v0, v1);
                    }
                    ptfrag[t * 8 + ((sp * 4 + gg) ^ (t & 7))] =
                        make_uint4(u[0], u[1], u[2], u[3]);
                }
        }

        // ---- hoist A fragments (registers for whole sweep)
        uint4 ahr[4], alr[4];
#pragma unroll
        for (int TL = 0; TL < 4; ++TL) {
            ahr[TL] = ptfrag[(TL * 16 + col) * 8 + sw0];
            alr[TL] = ptfrag[(TL * 16 + col) * 8 + sw1];
        }

        // ---- packed-key trackers (registers)
        unsigned m1k[4][4], m2k[4][4];
#pragma unroll
        for (int a = 0; a < 4; ++a)
#pragma unroll
            for (int b = 0; b < 4; ++b) { m1k[a][b] = 0xFFFFFFFFu; m2k[a][b] = 0xFFFFFFFFu; }

        int cndv = col;   // candidate id of this lane's column, += 16 per ct

        // ---- sweep: candidate fragments streamed from L2, zero barriers
#pragma unroll 2
        for (int ct = 0; ct < 32; ++ct) {
            const short8 bh = as_s8(scbq[ct * 128 + g * 32 + col]);
            const short8 bl = as_s8(scbq[ct * 128 + g * 32 + col + 16]);
            const float cK = snorm_l[ct * 16 + col] + K;   // 1 add (uniform-K)
            const f32x4 accin = {cK, cK, cK, cK};
#pragma unroll
            for (int TL = 0; TL < 4; ++TL) {
                const short8 ah = as_s8(ahr[TL]);
                const short8 al = as_s8(alr[TL]);
                f32x4 acc = __builtin_amdgcn_mfma_f32_16x16x32_bf16(ah, bh, accin, 0, 0, 0);
                acc = __builtin_amdgcn_mfma_f32_16x16x32_bf16(al, bh, acc, 0, 0, 0);
                acc = __builtin_amdgcn_mfma_f32_16x16x32_bf16(ah, bl, acc, 0, 0, 0);
#pragma unroll
                for (int i = 0; i < 4; ++i) {
                    const unsigned key = (__float_as_uint(acc[i]) & KMASK) | (unsigned)cndv;
                    // m2 = median(m2, m1, key); m1 = min(m1, key)  (R16-proven)
                    asm("v_med3_u32 %0, %1, %2, %3"
                        : "=v"(m2k[TL][i]) : "v"(m2k[TL][i]), "v"(m1k[TL][i]), "v"(key));
                    m1k[TL][i] = umn(m1k[TL][i], key);
                }
            }
            cndv += 16;
        }

        // ---- publish trackers (wave-internal LDS, R15-proven)
#pragma unroll
        for (int TL = 0; TL < 4; ++TL)
#pragma unroll
            for (int i = 0; i < 4; ++i) {
                const int pt = TL * 16 + 4 * g + i;
                m1key_s[pt * 17 + col] = m1k[TL][i];
                const float m2f = __uint_as_float(m2k[TL][i] & KMASK);
                m2h_s[pt * 17 + col] = __half_as_ushort(__float2half_rd(m2f));
            }

        // ---- R phase: admitted-id evals (SIMT) + wave-cooperative scans
        float bd = __builtin_inff(); int bi = 0;
        unsigned smask = 0;
        {
            unsigned mmk = 0xFFFFFFFFu;
#pragma unroll
            for (int c = 0; c < 16; ++c) mmk = umn(mmk, m1key_s[t * 17 + c]);
            const float thrf = __uint_as_float(mmk & KMASK) + (rr + ccm) * 0.001953125f;

            auto evalExact = [&](int cnd) {
                const f32x32 cvv = *(const f32x32*)(cbq + (long)cnd * RVQ_D);
                const float d = fmaf(-2.0f, tree_dot(r, cvv), rr) + snorm_l[cnd];
                if (d < bd || (d == bd && cnd < bi)) { bd = d; bi = cnd; }
            };
#pragma unroll 1
            for (int c = 0; c < 16; ++c) {
                const unsigned k1 = m1key_s[t * 17 + c];
                const bool adm = __uint_as_float(k1 & KMASK) <= thrf;
                const bool scn = __half2float(__ushort_as_half(m2h_s[t * 17 + c])) <= thrf;
                smask |= (scn ? 1u : 0u) << c;
                if (adm && !scn) evalExact((int)(k1 & 511u));
            }

            // cooperative full-class scans (rare; R15-proven)
            unsigned long long bal = __ballot(smask != 0);
            const int l31 = t & 31;
            while (bal) {
                const int b = (int)__builtin_ctzll(bal); bal &= bal - 1;
                unsigned sm = (unsigned)__shfl((int)smask, b, 64);
                f32x32 rb;
#pragma unroll
                for (int j = 0; j < RVQ_D; ++j) rb[j] = __shfl(r[j], b, 64);
                const float rrb = __shfl(rr, b, 64);
                while (sm) {
                    const int c = (int)__builtin_ctz(sm); sm &= sm - 1;
                    int  ci = l31 * 16 + c;
                    const f32x32 cvv = *(const f32x32*)(cbq + (long)ci * RVQ_D);
                    float d = fmaf(-2.0f, tree_dot(rb, cvv), rrb) + snorm_l[ci];
#pragma unroll
                    for (int m_ = 1; m_ <= 32; m_ <<= 1) {
                        const float od = __shfl_xor(d, m_, 64);
                        const int   oi = __shfl_xor(ci, m_, 64);
                        if (od < d || (od == d && oi < ci)) { d = od; ci = oi; }
                    }
                    if (t == b) {
                        if (d < bd || (d == bd && ci < bi)) { bd = d; bi = ci; }
                    }
                }
            }
        }

        iout[p * RVQ_Q + q] = (float)bi;
        const f32x32 gw = *(const f32x32*)(cbq + (long)bi * RVQ_D);
        r = st_update(r, gw);
    }
}

// ---------------------------------------------------------------------------
// Replay: bit-exact straight-through chain from stored indices (proven
// pre+post-timing R3-R16). Overwrites the scratch region with quantized.
__global__ __launch_bounds__(256) void rvq_replay(const float* __restrict__ z,
                                                  const float* __restrict__ cb,
                                                  float* __restrict__ out) {
    const int p = blockIdx.x * 256 + threadIdx.x;

    float r[RVQ_D], oacc[RVQ_D];
    {
        const float4* zp = (const float4*)(z + (long)p * RVQ_D);
#pragma unroll
        for (int w = 0; w < 8; ++w) {
            const float4 v = zp[w];
            r[w * 4 + 0] = v.x; r[w * 4 + 1] = v.y;
            r[w * 4 + 2] = v.z; r[w * 4 + 3] = v.w;
        }
    }
#pragma unroll
    for (int d = 0; d < RVQ_D; ++d) oacc[d] = 0.0f;

#pragma unroll 1
    for (int q = 0; q < RVQ_Q; ++q) {
        const int idx = (int)out[IDX_OFF + (long)p * RVQ_Q + q];
        const float4* cwb = (const float4*)(cb + ((long)q * RVQ_C + idx) * RVQ_D);
        float cwv[RVQ_D];
#pragma unroll
        for (int w = 0; w < 8; ++w) {
            const float4 v = cwb[w];
            cwv[w * 4 + 0] = v.x; cwv[w * 4 + 1] = v.y;
            cwv[w * 4 + 2] = v.z; cwv[w * 4 + 3] = v.w;
        }
#pragma unroll
        for (int d = 0; d < RVQ_D; ++d) {
            const float qst = r[d] + (cwv[d] - r[d]);
            oacc[d] += qst;
            r[d] = r[d] - qst;
        }
    }

    float4* qo = (float4*)(out + (long)p * RVQ_D);
#pragma unroll
    for (int w = 0; w < 8; ++w) {
        float4 v;
        v.x = oacc[w * 4 + 0]; v.y = oacc[w * 4 + 1];
        v.z = oacc[w * 4 + 2]; v.w = oacc[w * 4 + 3];
        qo[w] = v;
    }

    if (p < RVQ_Q) out[LOSS_OFF + p] = 0.0f;
}

// ---------------------------------------------------------------------------
extern "C" void kernel_launch(void* const* d_in, const int* in_sizes, int n_in,
                              void* d_out, int out_size, void* d_ws, size_t ws_size,
                              hipStream_t stream) {
    const float* z  = (const float*)d_in[0];
    const float* cb = (const float*)d_in[1];
    float* out = (float*)d_out;
    (void)d_ws; (void)ws_size;   // no workspace (R6 lesson)

    // scratch inside the quantized region (rewritten every call; replay
    // overwrites it at the end — R4/R5/R14/R15-proven pattern)
    uint4* scb   = (uint4*)out;                 // 655 KB fragments
    float* normg = out + NORM_OFF;              // 5120 exact norms
    float* iout  = out + IDX_OFF;

    rvq_prep  <<<(RVQ_Q * RVQ_C) / 64, 64, 0, stream>>>(cb, scb, normg);
    rvq_search<<<NPTS / BPTS, BPTS, 0, stream>>>(z, cb, scb, normg, iout);
    rvq_replay<<<NPTS / 256, 256, 0, stream>>>(z, cb, out);
}

// Round 18
// 516.148 us; speedup vs baseline: 1.1664x; 1.1277x over previous
//
#include <hip/hip_runtime.h>
#include <hip/hip_fp16.h>

// Residual VQ on MI355X (gfx950) — MFMA distance engine, barrier-free,
// packed-key tracker + wave-cooperative exact rescue.
// z: [8, 32768, 32] f32; codebooks: [10, 512, 32] f32.
// Outputs (flat f32 in d_out): quantized [B,N,D], indices [B,N,Q] (as float),
// commit_loss [Q] (zeros).
//
// R18 = R15 VERBATIM OPS (512 us, absmax 0.0) + LDS lifetime union:
// R17 showed trimming VALU ops HURTS at 1.7 waves/SIMD (they were hiding
// latency); the binding occupancy cap is LDS (17.4 KB -> 9 blocks/CU).
// ptfrag (8 KB: E-phase -> A-hoist) and m1key/m2h (6.4 KB: publish -> R)
// have disjoint lifetimes within a stage (single wave, program order), so
// they share one 8 KB region. LDS 17.4 -> 10.5 KB -> 15 blocks/CU (~45%
// occupancy, 2.1x). No other change: tracker (3-op C), per-point C-init,
// window 2^-9, fp16-rd m2, coop scans, prep/replay all bit-identical R15.

#define RVQ_Q 10
#define RVQ_C 512
#define RVQ_D 32

static constexpr int  NPTS      = 262144;
static constexpr long IDX_OFF   = (long)NPTS * RVQ_D;
static constexpr long LOSS_OFF  = IDX_OFF + (long)NPTS * RVQ_Q;
static constexpr int  BPTS      = 64;            // points per block (1 wave)
static constexpr int  SCB_U4    = RVQ_Q * 32 * 8 * 16;   // 40960 uint4
static constexpr long NORM_OFF  = (long)SCB_U4 * 4;      // floats into scratch
static constexpr unsigned KMASK = 0xFFFFFE00u;   // drop 9 bits for cnd

typedef __attribute__((ext_vector_type(32))) float f32x32;
typedef __attribute__((ext_vector_type(8)))  short short8;
typedef __attribute__((ext_vector_type(4)))  float f32x4;

// ---------------------------------------------------------------------------
// reference-exact numpy reduction tree (proven absmax 0.0 in R1/R3-R17)
__device__ __forceinline__ float tree_dot(const f32x32& x, const f32x32& y) {
    float a[8];
#pragma unroll
    for (int j = 0; j < 8; ++j) a[j] = x[j] * y[j];
#pragma unroll
    for (int j = 8; j < RVQ_D; ++j) a[j & 7] = fmaf(x[j], y[j], a[j & 7]);
    return ((a[0] + a[1]) + (a[2] + a[3])) + ((a[4] + a[5]) + (a[6] + a[7]));
}

__device__ __forceinline__ f32x32 st_update(const f32x32& r, const f32x32& gv) {
    const f32x32 tt  = gv - r;
    const f32x32 qst = r + tt;
    return r - qst;
}

__device__ __forceinline__ short8 as_s8(uint4 u) {
    union { uint4 a; short8 b; } x; x.a = u; return x.b;
}
__device__ __forceinline__ unsigned pk_hi(float v0, float v1) {
    return (__float_as_uint(v0) >> 16) | (__float_as_uint(v1) & 0xFFFF0000u);
}
__device__ __forceinline__ float lo_rem(float v) {
    return v - __uint_as_float(__float_as_uint(v) & 0xFFFF0000u);
}
__device__ __forceinline__ unsigned umn(unsigned a, unsigned b) { return a < b ? a : b; }
__device__ __forceinline__ unsigned umx(unsigned a, unsigned b) { return a > b ? a : b; }

// ---------------------------------------------------------------------------
// Kernel P: codebook -> bf16 hi/lo MFMA fragments + exact norms (R14-proven).
__global__ __launch_bounds__(64) void rvq_prep(const float* __restrict__ cb,
                                               uint4* __restrict__ scb,
                                               float* __restrict__ normg) {
    const int cnd = blockIdx.x * 64 + threadIdx.x;       // 0..5119
    const f32x32 c = *(const f32x32*)(cb + (long)cnd * RVQ_D);
    normg[cnd] = tree_dot(c, c);
    const int q = cnd >> 9, cq = cnd & 511, ct = cq >> 4, col = cq & 15;
    const long base = (long)(q * 32 + ct) * 128 + col;
#pragma unroll
    for (int g = 0; g < 4; ++g)
#pragma unroll
        for (int sp = 0; sp < 2; ++sp) {
            unsigned u[4];
#pragma unroll
            for (int pr = 0; pr < 4; ++pr) {
                const int j = g * 8 + pr * 2;
                float v0 = c[j], v1 = c[j + 1];
                if (sp == 1) { v0 = lo_rem(v0); v1 = lo_rem(v1); }
                u[pr] = pk_hi(v0, v1);
            }
            scb[base + (g * 2 + sp) * 16] = make_uint4(u[0], u[1], u[2], u[3]);
        }
}

// ---------------------------------------------------------------------------
// Kernel S: search. ONE wave per block, 64 points, no __syncthreads.
// LDS union: ptfrag (E->hoist) shares 8 KB with m1key/m2h (publish->R);
// lifetimes disjoint within a stage, single-wave program order makes it safe.
__global__ __launch_bounds__(64, 2) void rvq_search(const float* __restrict__ z,
                                                    const float* __restrict__ cb,
                                                    const uint4* __restrict__ scb,
                                                    const float* __restrict__ normg,
                                                    float* __restrict__ iout) {
    __shared__ __align__(16) unsigned char smem[BPTS * 8 * 16];   // 8 KB union
    __shared__ float snorm_l[RVQ_C];              // 2 KB exact norms
    __shared__ float rrbuf[BPTS];                 // 256 B

    uint4*          ptfrag  = (uint4*)smem;                          // 8 KB
    unsigned*       m1key_s = (unsigned*)smem;                       // 4.25 KB
    unsigned short* m2h_s   = (unsigned short*)(smem + BPTS * 17 * 4); // 2.1 KB

    const int t    = threadIdx.x;          // 0..63 == lane
    const int col  = t & 15;
    const int g    = t >> 4;
    const int sw0  = g ^ (col & 7);
    const int sw1  = (4 + g) ^ (col & 7);
    const long p   = (long)blockIdx.x * BPTS + t;

    f32x32 r = *(const f32x32*)(z + p * RVQ_D);

#pragma unroll 1
    for (int q = 0; q < RVQ_Q; ++q) {
        const float* cbq  = cb + (long)q * RVQ_C * RVQ_D;
        const uint4* scbq = scb + (long)q * 4096;

        // ---- norms -> LDS + ccm (wave max), rr + rrmax (wave max)
        float ccm = 0.0f;
#pragma unroll
        for (int n = 0; n < 8; ++n) {
            const float v = normg[q * RVQ_C + t + 64 * n];
            snorm_l[t + 64 * n] = v;
            ccm = fmaxf(ccm, v);
        }
#pragma unroll
        for (int m_ = 1; m_ <= 32; m_ <<= 1) ccm = fmaxf(ccm, __shfl_xor(ccm, m_, 64));

        const float rr = tree_dot(r, r);
        rrbuf[t] = rr;
        float rrmax = rr;
#pragma unroll
        for (int m_ = 1; m_ <= 32; m_ <<= 1) rrmax = fmaxf(rrmax, __shfl_xor(rrmax, m_, 64));
        const float biasW = (rrmax + ccm) * 0.001953125f;   // 2^-9 window

        // ---- E phase: -2r bf16 split -> ptfrag (proven bit-pattern)
        {
            const f32x32 s = -2.0f * r;
#pragma unroll
            for (int sp = 0; sp < 2; ++sp)
#pragma unroll
                for (int gg = 0; gg < 4; ++gg) {
                    unsigned u[4];
#pragma unroll
                    for (int pr = 0; pr < 4; ++pr) {
                        const int j = gg * 8 + pr * 2;
                        float v0 = s[j], v1 = s[j + 1];
                        if (sp == 1) { v0 = lo_rem(v0); v1 = lo_rem(v1); }
                        u[pr] = pk_hi(v0, v1);
                    }
                    ptfrag[t * 8 + ((sp * 4 + gg) ^ (t & 7))] =
                        make_uint4(u[0], u[1], u[2], u[3]);
                }
        }

        // ---- hoist A fragments + biased rr rows (registers for whole sweep)
        uint4 ahr[4], alr[4];
        float rrb4[4][4];
#pragma unroll
        for (int TL = 0; TL < 4; ++TL) {
            ahr[TL] = ptfrag[(TL * 16 + col) * 8 + sw0];
            alr[TL] = ptfrag[(TL * 16 + col) * 8 + sw1];
#pragma unroll
            for (int i = 0; i < 4; ++i)
                rrb4[TL][i] = rrbuf[TL * 16 + 4 * g + i] + biasW;
        }

        // ---- packed-key trackers (registers)
        unsigned m1k[4][4], m2k[4][4];
#pragma unroll
        for (int a = 0; a < 4; ++a)
#pragma unroll
            for (int b = 0; b < 4; ++b) { m1k[a][b] = 0xFFFFFFFFu; m2k[a][b] = 0xFFFFFFFFu; }

        int cndv = col;   // candidate id of this lane's column, += 16 per ct

        // ---- sweep: candidate fragments streamed from L2, zero barriers
#pragma unroll 2
        for (int ct = 0; ct < 32; ++ct) {
            const short8 bh = as_s8(scbq[ct * 128 + g * 32 + col]);
            const short8 bl = as_s8(scbq[ct * 128 + g * 32 + col + 16]);
            const float ccv = snorm_l[ct * 16 + col];
#pragma unroll
            for (int TL = 0; TL < 4; ++TL) {
                const short8 ah = as_s8(ahr[TL]);
                const short8 al = as_s8(alr[TL]);
                f32x4 acc = {rrb4[TL][0] + ccv, rrb4[TL][1] + ccv,
                             rrb4[TL][2] + ccv, rrb4[TL][3] + ccv};
                acc = __builtin_amdgcn_mfma_f32_16x16x32_bf16(ah, bh, acc, 0, 0, 0);
                acc = __builtin_amdgcn_mfma_f32_16x16x32_bf16(al, bh, acc, 0, 0, 0);
                acc = __builtin_amdgcn_mfma_f32_16x16x32_bf16(ah, bl, acc, 0, 0, 0);
#pragma unroll
                for (int i = 0; i < 4; ++i) {
                    const unsigned key = (__float_as_uint(acc[i]) & KMASK) | (unsigned)cndv;
                    m2k[TL][i] = umn(m2k[TL][i], umx(m1k[TL][i], key));
                    m1k[TL][i] = umn(m1k[TL][i], key);
                }
            }
            cndv += 16;
        }

        // ---- publish trackers (ptfrag region is dead; union reuse is safe
        //      in single-wave program order)
#pragma unroll
        for (int TL = 0; TL < 4; ++TL)
#pragma unroll
            for (int i = 0; i < 4; ++i) {
                const int pt = TL * 16 + 4 * g + i;
                m1key_s[pt * 17 + col] = m1k[TL][i];
                const float m2f = __uint_as_float(m2k[TL][i] & KMASK);
                m2h_s[pt * 17 + col] = __half_as_ushort(__float2half_rd(m2f));
            }

        // ---- R phase: admitted-id evals (SIMT) + wave-cooperative scans
        float bd = __builtin_inff(); int bi = 0;
        unsigned smask = 0;
        {
            unsigned mmk = 0xFFFFFFFFu;
#pragma unroll
            for (int c = 0; c < 16; ++c) mmk = umn(mmk, m1key_s[t * 17 + c]);
            const float thrf = __uint_as_float(mmk & KMASK) + (rr + ccm) * 0.001953125f;

            auto evalExact = [&](int cnd) {
                const f32x32 cvv = *(const f32x32*)(cbq + (long)cnd * RVQ_D);
                const float d = fmaf(-2.0f, tree_dot(r, cvv), rr) + snorm_l[cnd];
                if (d < bd || (d == bd && cnd < bi)) { bd = d; bi = cnd; }
            };
#pragma unroll 1
            for (int c = 0; c < 16; ++c) {
                const unsigned k1 = m1key_s[t * 17 + c];
                const bool adm = __uint_as_float(k1 & KMASK) <= thrf;
                const bool scn = __half2float(__ushort_as_half(m2h_s[t * 17 + c])) <= thrf;
                smask |= (scn ? 1u : 0u) << c;
                if (adm && !scn) evalExact((int)(k1 & 511u));
            }

            // cooperative full-class scans (rare; R15-proven)
            unsigned long long bal = __ballot(smask != 0);
            const int l31 = t & 31;
            while (bal) {
                const int b = (int)__builtin_ctzll(bal); bal &= bal - 1;
                unsigned sm = (unsigned)__shfl((int)smask, b, 64);
                f32x32 rb;
#pragma unroll
                for (int j = 0; j < RVQ_D; ++j) rb[j] = __shfl(r[j], b, 64);
                const float rrb = __shfl(rr, b, 64);
                while (sm) {
                    const int c = (int)__builtin_ctz(sm); sm &= sm - 1;
                    int  ci = l31 * 16 + c;
                    const f32x32 cvv = *(const f32x32*)(cbq + (long)ci * RVQ_D);
                    float d = fmaf(-2.0f, tree_dot(rb, cvv), rrb) + snorm_l[ci];
#pragma unroll
                    for (int m_ = 1; m_ <= 32; m_ <<= 1) {
                        const float od = __shfl_xor(d, m_, 64);
                        const int   oi = __shfl_xor(ci, m_, 64);
                        if (od < d || (od == d && oi < ci)) { d = od; ci = oi; }
                    }
                    if (t == b) {
                        if (d < bd || (d == bd && ci < bi)) { bd = d; bi = ci; }
                    }
                }
            }
        }

        iout[p * RVQ_Q + q] = (float)bi;
        const f32x32 gw = *(const f32x32*)(cbq + (long)bi * RVQ_D);
        r = st_update(r, gw);
    }
}

// ---------------------------------------------------------------------------
// Replay: bit-exact straight-through chain from stored indices (proven
// pre+post-timing R3-R17). Overwrites the scratch region with quantized.
__global__ __launch_bounds__(256) void rvq_replay(const float* __restrict__ z,
                                                  const float* __restrict__ cb,
                                                  float* __restrict__ out) {
    const int p = blockIdx.x * 256 + threadIdx.x;

    float r[RVQ_D], oacc[RVQ_D];
    {
        const float4* zp = (const float4*)(z + (long)p * RVQ_D);
#pragma unroll
        for (int w = 0; w < 8; ++w) {
            const float4 v = zp[w];
            r[w * 4 + 0] = v.x; r[w * 4 + 1] = v.y;
            r[w * 4 + 2] = v.z; r[w * 4 + 3] = v.w;
        }
    }
#pragma unroll
    for (int d = 0; d < RVQ_D; ++d) oacc[d] = 0.0f;

#pragma unroll 1
    for (int q = 0; q < RVQ_Q; ++q) {
        const int idx = (int)out[IDX_OFF + (long)p * RVQ_Q + q];
        const float4* cwb = (const float4*)(cb + ((long)q * RVQ_C + idx) * RVQ_D);
        float cwv[RVQ_D];
#pragma unroll
        for (int w = 0; w < 8; ++w) {
            const float4 v = cwb[w];
            cwv[w * 4 + 0] = v.x; cwv[w * 4 + 1] = v.y;
            cwv[w * 4 + 2] = v.z; cwv[w * 4 + 3] = v.w;
        }
#pragma unroll
        for (int d = 0; d < RVQ_D; ++d) {
            const float qst = r[d] + (cwv[d] - r[d]);
            oacc[d] += qst;
            r[d] = r[d] - qst;
        }
    }

    float4* qo = (float4*)(out + (long)p * RVQ_D);
#pragma unroll
    for (int w = 0; w < 8; ++w) {
        float4 v;
        v.x = oacc[w * 4 + 0]; v.y = oacc[w * 4 + 1];
        v.z = oacc[w * 4 + 2]; v.w = oacc[w * 4 + 3];
        qo[w] = v;
    }

    if (p < RVQ_Q) out[LOSS_OFF + p] = 0.0f;
}

// ---------------------------------------------------------------------------
extern "C" void kernel_launch(void* const* d_in, const int* in_sizes, int n_in,
                              void* d_out, int out_size, void* d_ws, size_t ws_size,
                              hipStream_t stream) {
    const float* z  = (const float*)d_in[0];
    const float* cb = (const float*)d_in[1];
    float* out = (float*)d_out;
    (void)d_ws; (void)ws_size;   // no workspace (R6 lesson)

    // scratch inside the quantized region (rewritten every call; replay
    // overwrites it at the end — R4/R5/R14-R17-proven pattern)
    uint4* scb   = (uint4*)out;                 // 655 KB fragments
    float* normg = out + NORM_OFF;              // 5120 exact norms
    float* iout  = out + IDX_OFF;

    rvq_prep  <<<(RVQ_Q * RVQ_C) / 64, 64, 0, stream>>>(cb, scb, normg);
    rvq_search<<<NPTS / BPTS, BPTS, 0, stream>>>(z, cb, scb, normg, iout);
    rvq_replay<<<NPTS / 256, 256, 0, stream>>>(z, cb, out);
}